// Round 2
// baseline (147.189 us; speedup 1.0000x reference)
//
#include <hip/hip_runtime.h>

// Problem constants (fixed by setup_inputs: bs=8, N=M=4096, C=128)
#define BS 8
#define NN 4096
#define MM 4096
#define CC 128
#define XT 128            // x rows per block
#define MH 2048           // y rows per block
#define JT 64             // y rows per j-step (2 wn-waves x 32)
#define NJ (MH / JT)      // 32 j-steps
#define NXT (NN / XT)     // 32 x-tiles

#define FINF_BITS 0x7F800000u

typedef __attribute__((ext_vector_type(8))) short bf16x8;
typedef __attribute__((ext_vector_type(4))) float f32x4;

// RNE fp32 -> bf16 (inputs are finite normals)
__device__ inline ushort f2bf(float f) {
    unsigned u = __float_as_uint(f);
    unsigned r = (u + 0x7FFFu + ((u >> 16) & 1u)) >> 16;
    return (ushort)r;
}

// ---------------------------------------------------------------------------
// prep (y only): fp32->bf16 copy of set2 + exact fp32 y norms +
// rowmin/colmin=+inf + out=0. x is converted inside ch_tile.
// ---------------------------------------------------------------------------
__global__ void ch_prep(const float* __restrict__ y,
                        ushort* __restrict__ y16, float* __restrict__ yn,
                        unsigned* __restrict__ rowmin, unsigned* __restrict__ colmin,
                        float* __restrict__ out) {
    int gid = blockIdx.x * blockDim.x + threadIdx.x;
    size_t i = (size_t)gid * 4;

    float4 w = *(const float4*)(y + i);
    ushort4 p;
    p.x = f2bf(w.x); p.y = f2bf(w.y); p.z = f2bf(w.z); p.w = f2bf(w.w);
    *(ushort4*)(y16 + i) = p;
    float sy = w.x * w.x + w.y * w.y + w.z * w.z + w.w * w.w;

#pragma unroll
    for (int mask = 1; mask <= 16; mask <<= 1)
        sy += __shfl_xor(sy, mask, 64);
    if ((threadIdx.x & 31) == 0)
        yn[gid >> 5] = sy;

    if (gid < BS * NN) rowmin[gid] = FINF_BITS;
    if (gid < BS * MM) colmin[gid] = FINF_BITS;
    if (gid == 0) out[0] = 0.0f;
}

// ---------------------------------------------------------------------------
// main kernel (R17): LDS-traffic elimination. R15/R16 were LDS-BW-bound:
// per CU per 128x128 y-tile, 384-448 KB of ds_read+staging vs 128 B/cyc peak
// (~3500 cyc) while MFMA needed only 621 cyc/SIMD -- occupancy (R16) didn't
// move MfmaUtil. Fix: (a) x fragments live in REGISTERS (af[4][4], 64 VGPR,
// loaded once from xs after the one-time conversion); (b) y fragments are
// loaded DIRECTLY from global y16 (L2-resident, 1 MB/XCD): one dwordx4 per
// frag = 16 rows x 64 B segments -> well coalesced; double-buffered yA/yB
// across j-tiles, NO __syncthreads in the main loop (no vmcnt(0) drains).
// Steady-state LDS = coltile atomics only. 256-thr blocks, wave tile 64x32,
// launch_bounds(256,2): VGPR<=256 -> 8 waves/CU = 2 desynced blocks/CU.
// ---------------------------------------------------------------------------
__global__ __launch_bounds__(256, 2) void ch_tile(
    const float* __restrict__ Xf, const ushort* __restrict__ Y,
    const float* __restrict__ yn,
    unsigned* __restrict__ rowmin, unsigned* __restrict__ colmin) {

    __shared__ ushort xs[XT * CC];       // 32 KB, chunk-swizzled (r&7), prologue only
    __shared__ unsigned coltile[MH];     // 8 KB
    __shared__ unsigned rowtile[XT];     // 0.5 KB
    __shared__ float xnorm[XT];          // 0.5 KB

    const int b  = blockIdx.x;           // 0..7 -> XCD pin (linear id % 8 == b)
    const int xt = blockIdx.y;           // 0..31
    const int mh = blockIdx.z;           // 0..1
    const int n0 = xt * XT;
    const int m0 = mh * MH;
    const int tid  = threadIdx.x;        // 0..255
    const int lane = tid & 63;
    const int wave = tid >> 6;           // 0..3
    const int lc   = lane & 15;          // A/B row, C col
    const int quad = lane >> 4;          // k-chunk, C row group
    const int wm = wave >> 1;            // x half (0/1)
    const int wn = wave & 1;             // y half of j-step (0/1)

    const ushort* Yb = Y + ((size_t)b * MM + m0) * CC;
    const float*  ynb = yn + (size_t)b * MM + m0;

    // ---- one-time: stage x tile fp32 -> bf16 -> swizzled LDS; norms too ----
    const float* Xb = Xf + ((size_t)b * NN + n0) * CC;
    {
        float psum[8];
#pragma unroll
        for (int s = 0; s < 8; ++s) {
            int flat = s * 256 + tid;    // 2048 chunks = 128 rows x 16
            int r = flat >> 4, c = flat & 15;
            float4 v0 = *(const float4*)(Xb + (size_t)r * CC + c * 8);
            float4 v1 = *(const float4*)(Xb + (size_t)r * CC + c * 8 + 4);
            ushort h[8] = {f2bf(v0.x), f2bf(v0.y), f2bf(v0.z), f2bf(v0.w),
                           f2bf(v1.x), f2bf(v1.y), f2bf(v1.z), f2bf(v1.w)};
            *(bf16x8*)(xs + r * CC + (c ^ (r & 7)) * 8) = *(bf16x8*)h;
            psum[s] = v0.x * v0.x + v0.y * v0.y + v0.z * v0.z + v0.w * v0.w +
                      v1.x * v1.x + v1.y * v1.y + v1.z * v1.z + v1.w * v1.w;
        }
#pragma unroll
        for (int mask = 1; mask <= 8; mask <<= 1)
#pragma unroll
            for (int s = 0; s < 8; ++s)
                psum[s] += __shfl_xor(psum[s], mask, 64);
        if ((tid & 15) == 0) {
#pragma unroll
            for (int s = 0; s < 8; ++s)
                xnorm[s * 16 + (tid >> 4)] = psum[s];
        }
    }
    for (int c2 = tid; c2 < MH; c2 += 256) coltile[c2] = FINF_BITS;
    if (tid < XT) rowtile[tid] = FINF_BITS;

    __syncthreads();   // xs + xnorm + coltile ready (only barrier before flush)

    // ---- hoist this wave's full A operand into registers: 64 rows x K=128 ----
    bf16x8 af[4][4];   // [k-chunk kt][row-group i] : 64 VGPR
    const int xrow = (wm * 64 + lc) * CC;
    const int xsw  = lc & 7;
#pragma unroll
    for (int kt = 0; kt < 4; ++kt)
#pragma unroll
        for (int i = 0; i < 4; ++i)
            af[kt][i] = *(const bf16x8*)(xs + xrow + i * 16 * CC +
                                         ((kt * 4 + quad) ^ xsw) * 8);

    float xnp[4][4];
#pragma unroll
    for (int i = 0; i < 4; ++i) {
        float4 t = *(const float4*)(&xnorm[wm * 64 + i * 16 + quad * 4]);
        xnp[i][0] = t.x; xnp[i][1] = t.y; xnp[i][2] = t.z; xnp[i][3] = t.w;
    }
    float rm[4][4];
#pragma unroll
    for (int i = 0; i < 4; ++i)
#pragma unroll
        for (int r = 0; r < 4; ++r) rm[i][r] = __builtin_inff();

    // ---- main loop: j-steps of 64 y rows, A/B software pipeline, no barriers ----
    auto loadt = [&](bf16x8 (&Yf)[4][2], float (&YN)[2], int j_) {
        const ushort* py = Yb + (size_t)(j_ * JT + wn * 32 + lc) * CC + quad * 8;
#pragma unroll
        for (int jj = 0; jj < 2; ++jj)
#pragma unroll
            for (int kt = 0; kt < 4; ++kt)
                Yf[kt][jj] = *(const bf16x8*)(py + jj * 16 * CC + kt * 32);
#pragma unroll
        for (int jj = 0; jj < 2; ++jj)
            YN[jj] = ynb[j_ * JT + wn * 32 + jj * 16 + lc];
    };

    auto compt = [&](bf16x8 (&Yf)[4][2], float (&YN)[2], int j_) {
        f32x4 acc[4][2];
        const f32x4 z = {0.f, 0.f, 0.f, 0.f};
#pragma unroll
        for (int kt = 0; kt < 4; ++kt) {
            __builtin_amdgcn_s_setprio(1);
#pragma unroll
            for (int jj = 0; jj < 2; ++jj)
#pragma unroll
                for (int i = 0; i < 4; ++i)
                    acc[i][jj] = __builtin_amdgcn_mfma_f32_16x16x32_bf16(
                        af[kt][i], Yf[kt][jj], (kt == 0) ? z : acc[i][jj], 0, 0, 0);
            __builtin_amdgcn_s_setprio(0);
        }

        // epilogue: d^2 mins (sqrt/clamp deferred)
        float cmv[2] = {__builtin_inff(), __builtin_inff()};
#pragma unroll
        for (int i = 0; i < 4; ++i) {
            f32x4 a0 = acc[i][0], a1 = acc[i][1];
            float e0[4], e1[4];
#pragma unroll
            for (int r = 0; r < 4; ++r) {
                e0[r] = xnp[i][r] + fmaf(-2.0f, a0[r], YN[0]);
                e1[r] = xnp[i][r] + fmaf(-2.0f, a1[r], YN[1]);
            }
#pragma unroll
            for (int r = 0; r < 4; ++r)
                rm[i][r] = fminf(rm[i][r], fminf(e0[r], e1[r]));  // v_min3
            cmv[0] = fminf(cmv[0],
                           fminf(fminf(e0[0], e0[1]), fminf(e0[2], e0[3])));
            cmv[1] = fminf(cmv[1],
                           fminf(fminf(e1[0], e1[1]), fminf(e1[2], e1[3])));
        }
#pragma unroll
        for (int mask = 16; mask <= 32; mask <<= 1)
#pragma unroll
            for (int jj = 0; jj < 2; ++jj)
                cmv[jj] = fminf(cmv[jj], __shfl_xor(cmv[jj], mask, 64));
        if (quad == 0) {
#pragma unroll
            for (int jj = 0; jj < 2; ++jj)
                atomicMin(&coltile[j_ * JT + wn * 32 + jj * 16 + lc],
                          __float_as_uint(fmaxf(cmv[jj], 0.0f)));
        }
    };

    bf16x8 yA[4][2], yB[4][2];
    float  ynA[2], ynB[2];
    loadt(yA, ynA, 0);
#pragma unroll 1
    for (int j = 0; j < NJ; j += 2) {
        loadt(yB, ynB, j + 1);
        compt(yA, ynA, j);
        if (j + 2 < NJ) loadt(yA, ynA, j + 2);
        compt(yB, ynB, j + 1);
    }

    // ---- row mins: reduce across the 16 lc lanes, LDS atomic once ----
#pragma unroll
    for (int mask = 1; mask <= 8; mask <<= 1)
#pragma unroll
        for (int i = 0; i < 4; ++i)
#pragma unroll
            for (int r = 0; r < 4; ++r)
                rm[i][r] = fminf(rm[i][r], __shfl_xor(rm[i][r], mask, 64));
    if (lc == 0) {
#pragma unroll
        for (int i = 0; i < 4; ++i)
#pragma unroll
            for (int r = 0; r < 4; ++r)
                atomicMin(&rowtile[wm * 64 + i * 16 + quad * 4 + r],
                          __float_as_uint(fmaxf(rm[i][r], 0.0f)));
    }

    // ---- flush tile minima with global atomics ----
    __syncthreads();
    if (tid < XT)
        atomicMin(&rowmin[(size_t)b * NN + n0 + tid], rowtile[tid]);
    for (int c2 = tid; c2 < MH; c2 += 256)
        atomicMin(&colmin[(size_t)b * MM + m0 + c2], coltile[c2]);
}

// ---------------------------------------------------------------------------
// finalize: total = (sum w1*sqrt(rowmin) + sum w2*sqrt(colmin)) / 2
// ---------------------------------------------------------------------------
__global__ void ch_finalize(const unsigned* __restrict__ rowmin,
                            const unsigned* __restrict__ colmin,
                            const float* __restrict__ w1,
                            const float* __restrict__ w2,
                            float* __restrict__ out) {
    int i = blockIdx.x * blockDim.x + threadIdx.x;
    int stride = gridDim.x * blockDim.x;
    float s = 0.f;
    for (int idx = i; idx < BS * NN; idx += stride)
        s += w1[idx] * sqrtf(__uint_as_float(rowmin[idx])) +
             w2[idx] * sqrtf(__uint_as_float(colmin[idx]));
#pragma unroll
    for (int off = 32; off > 0; off >>= 1) s += __shfl_down(s, off, 64);
    __shared__ float ls[4];
    int lane = threadIdx.x & 63, wv = threadIdx.x >> 6;
    if (lane == 0) ls[wv] = s;
    __syncthreads();
    if (threadIdx.x == 0) {
        float t = ls[0] + ls[1] + ls[2] + ls[3];
        atomicAdd(out, 0.5f * t);
    }
}

extern "C" void kernel_launch(void* const* d_in, const int* in_sizes, int n_in,
                              void* d_out, int out_size, void* d_ws, size_t ws_size,
                              hipStream_t stream) {
    const float* set1 = (const float*)d_in[0];
    const float* set2 = (const float*)d_in[1];
    const float* w1   = (const float*)d_in[2];
    const float* w2   = (const float*)d_in[3];
    float* out = (float*)d_out;

    // workspace layout (~8.5 MiB)
    ushort*   y16    = (ushort*)d_ws;                        // BS*MM*CC bf16 (8 MB)
    float*    yn     = (float*)(y16 + (size_t)BS * MM * CC); // 128 KB
    unsigned* rowmin = (unsigned*)(yn + BS * MM);            // 128 KB (d^2 bits)
    unsigned* colmin = rowmin + BS * NN;                     // 128 KB (d^2 bits)

    ch_prep<<<BS * MM * CC / 4 / 256, 256, 0, stream>>>(
        set2, y16, yn, rowmin, colmin, out);

    dim3 grid(BS, NXT, MM / MH);   // b fastest -> linear id % 8 == b == XCD
    ch_tile<<<grid, 256, 0, stream>>>(set1, y16, yn, rowmin, colmin);

    ch_finalize<<<64, 256, 0, stream>>>(rowmin, colmin, w1, w2, out);
}

// Round 4
// 125.387 us; speedup vs baseline: 1.1739x; 1.1739x over previous
//
#include <hip/hip_runtime.h>

// Problem constants (fixed by setup_inputs: bs=8, N=M=4096, C=128)
#define BS 8
#define NN 4096
#define MM 4096
#define CC 128
#define XT 128            // x rows per block
#define YT 128            // y rows per t-tile
#define MH 2048           // y rows per block
#define NMT (MH / YT)     // 16 y-tiles per block
#define NPH (2 * NMT)     // 32 half-K pipeline phases
#define NXT (NN / XT)     // 32 x-tiles
#define SLICE (YT * 64)   // ushorts per half-K slice (16 KB)

#define FINF_BITS 0x7F800000u

typedef __attribute__((ext_vector_type(8))) short bf16x8;
typedef __attribute__((ext_vector_type(4))) float f32x4;

// counted vmcnt wait (n = allowed outstanding VMEM ops)
#define WAITVn(n) asm volatile("s_waitcnt vmcnt(" #n ")" ::: "memory")
// rule #18: pin scheduling -- nothing may be reordered above the wait+barrier
#define SCHED_FENCE() __builtin_amdgcn_sched_barrier(0)

// RNE fp32 -> bf16 (inputs are finite normals)
__device__ inline ushort f2bf(float f) {
    unsigned u = __float_as_uint(f);
    unsigned r = (u + 0x7FFFu + ((u >> 16) & 1u)) >> 16;
    return (ushort)r;
}

// ---------------------------------------------------------------------------
// prep (y only): fp32->bf16 copy of set2 + exact fp32 y norms +
// rowmin/colmin=+inf + out=0. 8 elem/thread.
// ---------------------------------------------------------------------------
__global__ void ch_prep(const float* __restrict__ y,
                        ushort* __restrict__ y16, float* __restrict__ yn,
                        unsigned* __restrict__ rowmin, unsigned* __restrict__ colmin,
                        float* __restrict__ out) {
    int gid = blockIdx.x * blockDim.x + threadIdx.x;   // 524288 threads
    size_t i = (size_t)gid * 8;

    float4 w0 = *(const float4*)(y + i);
    float4 w1 = *(const float4*)(y + i + 4);
    ushort h[8] = {f2bf(w0.x), f2bf(w0.y), f2bf(w0.z), f2bf(w0.w),
                   f2bf(w1.x), f2bf(w1.y), f2bf(w1.z), f2bf(w1.w)};
    *(bf16x8*)(y16 + i) = *(bf16x8*)h;
    float sy = w0.x * w0.x + w0.y * w0.y + w0.z * w0.z + w0.w * w0.w +
               w1.x * w1.x + w1.y * w1.y + w1.z * w1.z + w1.w * w1.w;

#pragma unroll
    for (int mask = 1; mask <= 8; mask <<= 1)
        sy += __shfl_xor(sy, mask, 64);
    if ((threadIdx.x & 15) == 0)
        yn[gid >> 4] = sy;                 // 16 threads per 128-ch row

    if (gid < BS * NN) rowmin[gid] = FINF_BITS;
    if (gid < BS * MM) colmin[gid] = FINF_BITS;
    if (gid == 0) out[0] = 0.0f;
}

// stage one half-K slice (128 rows x 64 k = 16 KB) of y tile via
// global_load_lds width-16, dest lane-order, source chunk-swizzled c^(r&7).
// 256 threads: 1024 chunks -> 4 iterations. Counts 4 on vmcnt per wave.
__device__ __forceinline__ void stage_y(const ushort* __restrict__ Yb,
                                        ushort* __restrict__ buf,
                                        int tile, int half, int tid, int wave) {
#pragma unroll
    for (int s = 0; s < 4; ++s) {
        int f = s * 256 + tid;           // 1024 chunks = 128 rows x 8
        int r = f >> 3, cslot = f & 7;
        const ushort* g = Yb + (size_t)(tile * YT + r) * CC + half * 64 +
                          ((cslot ^ (r & 7)) * 8);
        ushort* l = buf + (size_t)(s * 256 + wave * 64) * 8;  // uniform; HW adds lane*16
        __builtin_amdgcn_global_load_lds(
            (const __attribute__((address_space(1))) void*)g,
            (__attribute__((address_space(3))) void*)l, 16, 0, 0);
    }
}

// ---------------------------------------------------------------------------
// main kernel (R19 = R18 + rule-#18 sched fences): hybrid x-in-reg +
// y-in-LDS + counted-vmcnt pipeline.
// R15/R16 were LDS-BW-bound (224 KB LDS traffic per 128x128 tile vs
// 112 B/cyc/CU); R17 (y direct from L2) was L2-BW-bound (234 B/cyc needed
// vs ~56 ceiling). Fix: x fragments hoisted ONCE to registers (af[4][4],
// 64 VGPR) -- LDS traffic per phase drops to y only (96 KB/CU-phase =
// 77 B/cyc < 112); y flows through LDS so L2 traffic is 26 B/cyc < 56.
// MFMA becomes the binding pipe (~16.5 us floor). The per-phase
// __syncthreads vmcnt(0) drain is replaced by a 3-buffer half-K pipeline
// with s_waitcnt vmcnt(4) + raw s_barrier (stage slice ph+2 during phase
// ph; only slice ph+1 must have landed at the barrier). Each wait+barrier
// is followed by sched_barrier(0): raw s_barrier is NOT a compiler memory
// fence, and hipcc can hoist LDS reads past inline-asm waitcnt (guide rule
// #18) -- the fence pins program order. yn staged to LDS in the prologue so
// the loop has ZERO compiler-tracked VMEM loads (vmcnt counts stay exact).
// xs region aliased by the y slice buffers: saves LDS (65 KB total -> 2
// blocks/CU) and stops the compiler rematerializing af from LDS.
// ---------------------------------------------------------------------------
__global__ __launch_bounds__(256, 2) void ch_tile(
    const float* __restrict__ Xf, const ushort* __restrict__ Y,
    const float* __restrict__ yn,
    unsigned* __restrict__ rowmin, unsigned* __restrict__ colmin) {

    __shared__ ushort pool[3 * SLICE];   // 48 KB: xs (32 KB) then 3 y slices
    __shared__ unsigned coltile[MH];     // 8 KB
    __shared__ unsigned rowtile[XT];     // 0.5 KB
    __shared__ float xnorm[XT];          // 0.5 KB
    __shared__ float ynld[MH];           // 8 KB (block's y norms)

    const int b  = blockIdx.x;           // 0..7 -> XCD pin (linear id % 8 == b)
    const int xt = blockIdx.y;           // 0..31
    const int mh = blockIdx.z;           // 0..1
    const int n0 = xt * XT;
    const int m0 = mh * MH;
    const int tid  = threadIdx.x;        // 0..255
    const int lane = tid & 63;
    const int wave = tid >> 6;           // 0..3
    const int lc   = lane & 15;          // A/B row, C col
    const int quad = lane >> 4;          // k-chunk, C row group
    const int wm = wave >> 1;            // x half (0/1)
    const int wn = wave & 1;             // y half (0/1)

    const ushort* Yb = Y + ((size_t)b * MM + m0) * CC;

    // ---- prologue A: stage x tile fp32 -> bf16 -> swizzled LDS (xs = pool);
    //      x norms; y norms -> LDS; coltile/rowtile init ----
    ushort* xs = pool;
    const float* Xb = Xf + ((size_t)b * NN + n0) * CC;
    {
        float psum[8];
#pragma unroll
        for (int s = 0; s < 8; ++s) {
            int flat = s * 256 + tid;    // 2048 chunks = 128 rows x 16
            int r = flat >> 4, c = flat & 15;
            float4 v0 = *(const float4*)(Xb + (size_t)r * CC + c * 8);
            float4 v1 = *(const float4*)(Xb + (size_t)r * CC + c * 8 + 4);
            ushort h[8] = {f2bf(v0.x), f2bf(v0.y), f2bf(v0.z), f2bf(v0.w),
                           f2bf(v1.x), f2bf(v1.y), f2bf(v1.z), f2bf(v1.w)};
            *(bf16x8*)(xs + r * CC + (c ^ (r & 7)) * 8) = *(bf16x8*)h;
            psum[s] = v0.x * v0.x + v0.y * v0.y + v0.z * v0.z + v0.w * v0.w +
                      v1.x * v1.x + v1.y * v1.y + v1.z * v1.z + v1.w * v1.w;
        }
#pragma unroll
        for (int mask = 1; mask <= 8; mask <<= 1)
#pragma unroll
            for (int s = 0; s < 8; ++s)
                psum[s] += __shfl_xor(psum[s], mask, 64);
        if ((tid & 15) == 0) {
#pragma unroll
            for (int s = 0; s < 8; ++s)
                xnorm[s * 16 + (tid >> 4)] = psum[s];
        }
    }
    {
        const float* ynb = yn + (size_t)b * MM + m0;
#pragma unroll
        for (int s = 0; s < MH / 256; ++s)
            ynld[s * 256 + tid] = ynb[s * 256 + tid];
    }
    for (int c2 = tid; c2 < MH; c2 += 256) coltile[c2] = FINF_BITS;
    if (tid < XT) rowtile[tid] = FINF_BITS;

    __syncthreads();   // xs + xnorm + ynld + coltile ready

    // ---- prologue B: hoist this wave's A operand + norms into registers ----
    bf16x8 af[4][4];   // [k-chunk32 kt][row-group i] : 64 VGPR
    const int xrow = (wm * 64 + lc) * CC;
    const int xsw  = lc & 7;
#pragma unroll
    for (int kt = 0; kt < 4; ++kt)
#pragma unroll
        for (int i = 0; i < 4; ++i)
            af[kt][i] = *(const bf16x8*)(xs + xrow + i * 16 * CC +
                                         ((kt * 4 + quad) ^ xsw) * 8);

    float xnp[4][4];
#pragma unroll
    for (int i = 0; i < 4; ++i) {
        float4 t = *(const float4*)(&xnorm[wm * 64 + i * 16 + quad * 4]);
        xnp[i][0] = t.x; xnp[i][1] = t.y; xnp[i][2] = t.z; xnp[i][3] = t.w;
    }
    float rm[4][4];
#pragma unroll
    for (int i = 0; i < 4; ++i)
#pragma unroll
        for (int r = 0; r < 4; ++r) rm[i][r] = __builtin_inff();

    __syncthreads();   // all waves done reading xs: pool may be overwritten

    // ---- prologue C: stage slices 0,1 into buffers 0,1 ----
    stage_y(Yb, pool + 0 * SLICE, 0, 0, tid, wave);
    stage_y(Yb, pool + 1 * SLICE, 0, 1, tid, wave);
    WAITVn(4);                       // slice 0 landed; slice 1 in flight
    __builtin_amdgcn_s_barrier();
    SCHED_FENCE();

    int rd = 0;                      // buffer holding the current slice
#pragma unroll 1
    for (int t = 0; t < NMT; ++t) {
        f32x4 acc[4][4];
        const f32x4 z = {0.f, 0.f, 0.f, 0.f};
        float ynr[4];

        // ================= phase h=0 (k 0..63) =================
        {
            const int ph = 2 * t;
            const ushort* ybuf = pool + rd * SLICE;
            if (ph + 2 < NPH) {
                int wr = rd + 2; if (wr >= 3) wr -= 3;
                stage_y(Yb, pool + wr * SLICE, (ph + 2) >> 1, (ph + 2) & 1,
                        tid, wave);
            }
#pragma unroll
            for (int j = 0; j < 4; ++j)       // LDS read: no vmcnt impact
                ynr[j] = ynld[t * YT + wn * 64 + j * 16 + lc];
#pragma unroll
            for (int s2 = 0; s2 < 2; ++s2) {
                bf16x8 yf[4];
                const int cy = ((s2 * 4 + quad) ^ xsw) * 8;
#pragma unroll
                for (int j = 0; j < 4; ++j)
                    yf[j] = *(const bf16x8*)(ybuf + (wn * 64 + j * 16 + lc) * 64 + cy);
                __builtin_amdgcn_s_setprio(1);
#pragma unroll
                for (int j = 0; j < 4; ++j)
#pragma unroll
                    for (int i = 0; i < 4; ++i)
                        acc[i][j] = __builtin_amdgcn_mfma_f32_16x16x32_bf16(
                            af[s2][i], yf[j], (s2 == 0) ? z : acc[i][j], 0, 0, 0);
                __builtin_amdgcn_s_setprio(0);
            }
            SCHED_FENCE();                    // keep reads/MFMA above the wait
            if (ph + 2 < NPH) { WAITVn(4); } else { WAITVn(0); }
            __builtin_amdgcn_s_barrier();
            SCHED_FENCE();                    // nothing from below moves up
            rd = (rd == 2) ? 0 : rd + 1;
        }

        // ================= phase h=1 (k 64..127) =================
        {
            const int ph = 2 * t + 1;
            const ushort* ybuf = pool + rd * SLICE;
            if (ph + 2 < NPH) {
                int wr = rd + 2; if (wr >= 3) wr -= 3;
                stage_y(Yb, pool + wr * SLICE, (ph + 2) >> 1, (ph + 2) & 1,
                        tid, wave);
            }
#pragma unroll
            for (int s2 = 0; s2 < 2; ++s2) {
                bf16x8 yf[4];
                const int cy = ((s2 * 4 + quad) ^ xsw) * 8;
#pragma unroll
                for (int j = 0; j < 4; ++j)
                    yf[j] = *(const bf16x8*)(ybuf + (wn * 64 + j * 16 + lc) * 64 + cy);
                __builtin_amdgcn_s_setprio(1);
#pragma unroll
                for (int j = 0; j < 4; ++j)
#pragma unroll
                    for (int i = 0; i < 4; ++i)
                        acc[i][j] = __builtin_amdgcn_mfma_f32_16x16x32_bf16(
                            af[2 + s2][i], yf[j], acc[i][j], 0, 0, 0);
                __builtin_amdgcn_s_setprio(0);
            }

            // ---- epilogue: d^2 mins (sqrt/clamp deferred) ----
            float cmv[4];
#pragma unroll
            for (int j = 0; j < 4; ++j) cmv[j] = __builtin_inff();
#pragma unroll
            for (int i = 0; i < 4; ++i) {
#pragma unroll
                for (int j = 0; j < 4; ++j) {
                    f32x4 a = acc[i][j];
                    float e[4];
#pragma unroll
                    for (int r = 0; r < 4; ++r)
                        e[r] = xnp[i][r] + fmaf(-2.0f, a[r], ynr[j]);
#pragma unroll
                    for (int r = 0; r < 4; ++r)
                        rm[i][r] = fminf(rm[i][r], e[r]);
                    cmv[j] = fminf(cmv[j],
                                   fminf(fminf(e[0], e[1]), fminf(e[2], e[3])));
                }
            }
#pragma unroll
            for (int mask = 16; mask <= 32; mask <<= 1)
#pragma unroll
                for (int j = 0; j < 4; ++j)
                    cmv[j] = fminf(cmv[j], __shfl_xor(cmv[j], mask, 64));
            if (quad == 0) {
#pragma unroll
                for (int j = 0; j < 4; ++j)
                    atomicMin(&coltile[t * YT + wn * 64 + j * 16 + lc],
                              __float_as_uint(fmaxf(cmv[j], 0.0f)));
            }

            SCHED_FENCE();
            if (ph + 2 < NPH) { WAITVn(4); } else { WAITVn(0); }
            __builtin_amdgcn_s_barrier();
            SCHED_FENCE();
            rd = (rd == 2) ? 0 : rd + 1;
        }
    }

    // ---- row mins: reduce across the 16 lc lanes, LDS atomic once ----
#pragma unroll
    for (int mask = 1; mask <= 8; mask <<= 1)
#pragma unroll
        for (int i = 0; i < 4; ++i)
#pragma unroll
            for (int r = 0; r < 4; ++r)
                rm[i][r] = fminf(rm[i][r], __shfl_xor(rm[i][r], mask, 64));
    if (lc == 0) {
#pragma unroll
        for (int i = 0; i < 4; ++i)
#pragma unroll
            for (int r = 0; r < 4; ++r)
                atomicMin(&rowtile[wm * 64 + i * 16 + quad * 4 + r],
                          __float_as_uint(fmaxf(rm[i][r], 0.0f)));
    }

    // ---- flush tile minima with global atomics ----
    __syncthreads();
    if (tid < XT)
        atomicMin(&rowmin[(size_t)b * NN + n0 + tid], rowtile[tid]);
    for (int c2 = tid; c2 < MH; c2 += 256)
        atomicMin(&colmin[(size_t)b * MM + m0 + c2], coltile[c2]);
}

// ---------------------------------------------------------------------------
// finalize: total = (sum w1*sqrt(rowmin) + sum w2*sqrt(colmin)) / 2
// ---------------------------------------------------------------------------
__global__ void ch_finalize(const unsigned* __restrict__ rowmin,
                            const unsigned* __restrict__ colmin,
                            const float* __restrict__ w1,
                            const float* __restrict__ w2,
                            float* __restrict__ out) {
    int i = blockIdx.x * blockDim.x + threadIdx.x;
    int stride = gridDim.x * blockDim.x;
    float s = 0.f;
    for (int idx = i; idx < BS * NN; idx += stride)
        s += w1[idx] * sqrtf(__uint_as_float(rowmin[idx])) +
             w2[idx] * sqrtf(__uint_as_float(colmin[idx]));
#pragma unroll
    for (int off = 32; off > 0; off >>= 1) s += __shfl_down(s, off, 64);
    __shared__ float ls[4];
    int lane = threadIdx.x & 63, wv = threadIdx.x >> 6;
    if (lane == 0) ls[wv] = s;
    __syncthreads();
    if (threadIdx.x == 0) {
        float t = ls[0] + ls[1] + ls[2] + ls[3];
        atomicAdd(out, 0.5f * t);
    }
}

extern "C" void kernel_launch(void* const* d_in, const int* in_sizes, int n_in,
                              void* d_out, int out_size, void* d_ws, size_t ws_size,
                              hipStream_t stream) {
    const float* set1 = (const float*)d_in[0];
    const float* set2 = (const float*)d_in[1];
    const float* w1   = (const float*)d_in[2];
    const float* w2   = (const float*)d_in[3];
    float* out = (float*)d_out;

    // workspace layout (~8.5 MiB)
    ushort*   y16    = (ushort*)d_ws;                        // BS*MM*CC bf16 (8 MB)
    float*    yn     = (float*)(y16 + (size_t)BS * MM * CC); // 128 KB
    unsigned* rowmin = (unsigned*)(yn + BS * MM);            // 128 KB (d^2 bits)
    unsigned* colmin = rowmin + BS * NN;                     // 128 KB (d^2 bits)

    ch_prep<<<BS * MM * CC / 8 / 256, 256, 0, stream>>>(
        set2, y16, yn, rowmin, colmin, out);

    dim3 grid(BS, NXT, MM / MH);   // b fastest -> linear id % 8 == b == XCD
    ch_tile<<<grid, 256, 0, stream>>>(set1, y16, yn, rowmin, colmin);

    ch_finalize<<<64, 256, 0, stream>>>(rowmin, colmin, w1, w2, out);
}